// Round 4
// baseline (322.199 us; speedup 1.0000x reference)
//
#include <hip/hip_runtime.h>

#define NN     256
#define NF     127
#define DIM    128
#define NH     8
#define DH     64
#define INNER  512
#define DEPTH  6
#define NB     512
#define TB     1024       // threads per block (16 waves)
#define ATTN_SCALE 0.125f
#define LN_EPS 1e-5f

#define FMA4(A_, S_, V_) { A_.x=fmaf(S_,(V_).x,A_.x); A_.y=fmaf(S_,(V_).y,A_.y); \
                           A_.z=fmaf(S_,(V_).z,A_.z); A_.w=fmaf(S_,(V_).w,A_.w); }

__device__ __forceinline__ float wred_sum(float v){
#pragma unroll
  for(int o=32;o;o>>=1) v += __shfl_xor(v,o);
  return v;
}
__device__ __forceinline__ float wred_max(float v){
#pragma unroll
  for(int o=32;o;o>>=1) v = fmaxf(v,__shfl_xor(v,o));
  return v;
}
__device__ __forceinline__ float2 wred_sum2(float a, float b){
#pragma unroll
  for(int o=32;o;o>>=1){ a += __shfl_xor(a,o); b += __shfl_xor(b,o); }
  return make_float2(a,b);
}

// In-wave LayerNorm of a 128-dim row held as (n0,n1) = dims (l, l+64) per lane.
__device__ __forceinline__ void ln_wave(float n0, float n1,
                                        const float* g, const float* b, int l,
                                        float& x0, float& x1){
  float2 sv = wred_sum2(n0+n1, n0*n0+n1*n1);
  float m  = sv.x*(1.f/DIM);
  float var = sv.y*(1.f/DIM) - m*m;
  float rs = rsqrtf(var + LN_EPS);
  x0 = (n0-m)*rs*g[l]    + b[l];
  x1 = (n1-m)*rs*g[64+l] + b[64+l];
}

// In-wave gated residual. No barriers.
__device__ __forceinline__ void gate_wave(float o0, float o1, float& n0, float& n1,
                                          const float* Wg, int l){
  float gv = o0*Wg[l]    + n0*Wg[DIM+l]    + (o0-n0)*Wg[2*DIM+l]
           + o1*Wg[64+l] + n1*Wg[DIM+64+l] + (o1-n1)*Wg[2*DIM+64+l];
  gv = wred_sum(gv);
  float gate = 1.f/(1.f + expf(-gv));
  n0 = o0*gate + n0*(1.f-gate);
  n1 = o1*gate + n1*(1.f-gate);
}

// ---- matvec partials, 1024-thread variants (SC = 4096 floats) ----
// x[128] @ W[128][512] -> SC[fo*512+c], fo in [0,8)
__device__ __forceinline__ void mvp128_512(const float* xin, const float* W,
                                           float* SC, int t){
  const int cg4 = (t&127)<<2, fo = t>>7;
  float4 acc = make_float4(0.f,0.f,0.f,0.f);
#pragma unroll
  for(int f=fo*16; f<fo*16+16; f++){
    float4 wv = *(const float4*)(W + f*INNER + cg4);
    float xv = xin[f];
    FMA4(acc, xv, wv);
  }
  *(float4*)(SC + fo*INNER + cg4) = acc;
}
// x[128] @ W[128][1024] -> SC[fq*1024+c], fq in [0,4)
__device__ __forceinline__ void mvp128_1024(const float* xin, const float* W,
                                            float* SC, int t){
  const int cg4 = (t&255)<<2, fq = t>>8;
  float4 acc = make_float4(0.f,0.f,0.f,0.f);
#pragma unroll
  for(int f=fq*32; f<fq*32+32; f++){
    float4 wv = *(const float4*)(W + f*(2*INNER) + cg4);
    float xv = xin[f];
    FMA4(acc, xv, wv);
  }
  *(float4*)(SC + fq*(2*INNER) + cg4) = acc;
}
// a[512] @ W[512][128] -> SC[fg*128+c], fg in [0,32)
__device__ __forceinline__ void mvp512_128(const float* ain, const float* W,
                                           float* SC, int t){
  const int cg4 = (t&31)<<2, fg = t>>5;
  float4 acc = make_float4(0.f,0.f,0.f,0.f);
#pragma unroll
  for(int f=fg*16; f<fg*16+16; f++){
    float4 wv = *(const float4*)(W + f*DIM + cg4);
    float av = ain[f];
    FMA4(acc, av, wv);
  }
  *(float4*)(SC + fg*DIM + cg4) = acc;
}

// LN1 output xs[128] (LDS) -> next-layer q/k/v. 3 barriers inside (B+1..B+3).
__device__ __forceinline__ void qkv_tail(const float* xs, int i,
    const float* Wq, const float* bq, const float* Wkv, const float* bkv,
    const float* be, float* qgn, float* kTn, float* vgn, float* SC, int t){
  mvp128_512(xs, Wq, SC, t);
  __syncthreads();
  if(t < INNER){
    float s = bq[t];
#pragma unroll
    for(int fo=0; fo<8; fo++) s += SC[fo*INNER + t];
    qgn[i*INNER + t] = s;
  }
  __syncthreads();                 // SC reuse
  mvp128_1024(xs, Wkv, SC, t);
  __syncthreads();
  {
    int c = t;                     // 1024 threads cover 1024 cols
    float s = bkv[c];
#pragma unroll
    for(int fq=0; fq<4; fq++) s += SC[fq*(2*INNER) + c];
    if(c < INNER) kTn[c*NN + i]            = s + be[c];
    else          vgn[i*INNER + c - INNER] = s + be[c-INNER];
  }
}

// ---- layer 0: node-init + LN1 (in-wave) + QKV ----
__global__ __launch_bounds__(TB) void k_qkv0(const float* atom_emb, const float* noise,
    float* nodes, const float* ln1_g, const float* ln1_b,
    const float* Wq, const float* bq, const float* Wkv, const float* bkv, const float* be,
    float* qg, float* kT, float* vg){
  __shared__ __align__(16) float SC[4096];
  __shared__ __align__(16) float xsm[DIM];
  const int t = threadIdx.x, i = blockIdx.x;
  const int w = t>>6, l = t&63;
  float nd0 = (l<NF)?    atom_emb[i*NF + l]      : noise[0];
  float nd1 = (64+l<NF)? atom_emb[i*NF + 64 + l] : noise[0];
  if(w==0){ nodes[i*DIM + l] = nd0; nodes[i*DIM + 64 + l] = nd1; }
  float x0, x1;
  ln_wave(nd0, nd1, ln1_g, ln1_b, l, x0, x1);
  xsm[l] = x0; xsm[64+l] = x1;     // all waves write identical values (benign)
  __syncthreads();
  qkv_tail(xsm, i, Wq, bq, Wkv, bkv, be, qg, kT, vg, SC, t);
}

// ---- fused per-row layer, 16 waves: 2 waves per attention head ----
__global__ __launch_bounds__(TB) void k_layer(
    float* nodes, const float* qg, const float* kT, const float* vg,
    float* qg_n, float* kT_n, float* vg_n,
    const int* bonds, const float* coords,
    const float* We,
    const float* Wo, const float* bo, const float* Wg1,
    const float* ln2_g, const float* ln2_b,
    const float* W1, const float* b1, const float* W2, const float* b2,
    const float* Wg2,
    const float* ln1_g_n, const float* ln1_b_n,
    const float* Wq_n, const float* bq_n, const float* Wkv_n, const float* bkv_n,
    const float* be_n,
    const float* out_w, const float* out_b, float* eout, int has_next)
{
  __shared__ __align__(16) float SC[4096];   // QK partials during attn; matmul partials after
  __shared__ __align__(16) float aW[NH*NN];  // attention weights
  __shared__ __align__(16) float aoP[2*NH*DH]; // PV partials (2 j-halves)
  __shared__ __align__(16) float cEs[NH*3];  // edge moments per head
  __shared__ __align__(16) float qs[INNER];  // q row; later FFN hidden
  __shared__ __align__(16) float ao[INNER];  // attention output row
  __shared__ __align__(16) float eb[3*NN];   // edge planes [c][j]
  __shared__ __align__(16) float xsm[DIM];
  __shared__ __align__(16) float o128[DIM];
  const int t = threadIdx.x, i = blockIdx.x;
  const int w = t>>6, l = t&63;

  // ---- init ----
  if(t < INNER) qs[t] = qg[i*INNER + t];
  if(t < 3*NN)  eb[t] = 0.f;
  float nd0 = nodes[i*DIM + l];        // per-wave redundant row state
  float nd1 = nodes[i*DIM + 64 + l];
  __syncthreads();                               // B1

  // ---- scatter bonds touching row i ----
  if(t < NB){
    const int bi = bonds[2*t], bj = bonds[2*t+1];
    if(bi==i || bj==i){
      float dx = coords[3*bi+0] - coords[3*bj+0];
      float dy = coords[3*bi+1] - coords[3*bj+1];
      float dz = coords[3*bi+2] - coords[3*bj+2];
      if(bi==i){ eb[bj]=dx;  eb[NN+bj]=dy;  eb[2*NN+bj]=dz;  }
      if(bj==i){ eb[bi]=-dx; eb[NN+bi]=-dy; eb[2*NN+bi]=-dz; }
    }
  }
  __syncthreads();                               // B2

  // ---- attention: head h = w>>1, o/j-half = w&1 ----
  {
    const int h = w>>1, half = w&1, j0 = l<<2, qb = h*DH;
    // qwe_c = q[h-slice] . We[c, h-slice]  (redundant in both waves of the pair)
    float qwe0, qwe1, qwe2;
    {
      float qv = qs[qb + l];
      qwe0 = qv*We[0*INNER + qb + l];
      qwe1 = qv*We[1*INNER + qb + l];
      qwe2 = qv*We[2*INNER + qb + l];
#pragma unroll
      for(int o=32;o;o>>=1){
        qwe0 += __shfl_xor(qwe0,o); qwe1 += __shfl_xor(qwe1,o); qwe2 += __shfl_xor(qwe2,o);
      }
    }
    // QK^T partial over this wave's o-half
    const float* kTh = kT + qb*NN;
    float s0=0.f,s1=0.f,s2=0.f,s3=0.f;
#pragma unroll
    for(int o=half*32; o<half*32+32; o++){
      float qv = qs[qb + o];
      float4 kk = *(const float4*)(kTh + o*NN + j0);
      s0=fmaf(qv,kk.x,s0); s1=fmaf(qv,kk.y,s1); s2=fmaf(qv,kk.z,s2); s3=fmaf(qv,kk.w,s3);
    }
    *(float4*)(SC + (half*NH + h)*NN + j0) = make_float4(s0,s1,s2,s3);
    __syncthreads();                             // B3
    // combine halves + edges + softmax (redundant in pair)
    float4 pA = *(const float4*)(SC + h*NN + j0);
    float4 pB = *(const float4*)(SC + (NH+h)*NN + j0);
    float4 ex = *(const float4*)(eb + j0);
    float4 ey = *(const float4*)(eb + NN + j0);
    float4 ez = *(const float4*)(eb + 2*NN + j0);
    s0 = (pA.x+pB.x + qwe0*ex.x + qwe1*ey.x + qwe2*ez.x)*ATTN_SCALE;
    s1 = (pA.y+pB.y + qwe0*ex.y + qwe1*ey.y + qwe2*ez.y)*ATTN_SCALE;
    s2 = (pA.z+pB.z + qwe0*ex.z + qwe1*ey.z + qwe2*ez.z)*ATTN_SCALE;
    s3 = (pA.w+pB.w + qwe0*ex.w + qwe1*ey.w + qwe2*ez.w)*ATTN_SCALE;
    float mx = wred_max(fmaxf(fmaxf(s0,s1),fmaxf(s2,s3)));
    float p0=expf(s0-mx), p1=expf(s1-mx), p2=expf(s2-mx), p3=expf(s3-mx);
    float inv = 1.f / wred_sum(p0+p1+p2+p3);
    float a0=p0*inv, a1=p1*inv, a2=p2*inv, a3=p3*inv;
    if(half==0) *(float4*)(aW + h*NN + j0) = make_float4(a0,a1,a2,a3);
    // edge moments (redundant; only half==0 lane 0 publishes)
    float c0 = a0*ex.x + a1*ex.y + a2*ex.z + a3*ex.w;
    float c1 = a0*ey.x + a1*ey.y + a2*ey.z + a3*ey.w;
    float c2 = a0*ez.x + a1*ez.y + a2*ez.z + a3*ez.w;
    c0 = wred_sum(c0); c1 = wred_sum(c1); c2 = wred_sum(c2);
    if(half==0 && l==0){ cEs[h*3+0]=c0; cEs[h*3+1]=c1; cEs[h*3+2]=c2; }
    __syncthreads();                             // B4 (aW, cEs ready)
    // PV over this wave's j-half: lane -> dims dq..dq+3, jg covers 32 j
    const int dq = (l&15)<<2, jg = l>>4;
    const float* vb = vg + qb + dq;
    float4 acc = make_float4(0.f,0.f,0.f,0.f);
#pragma unroll
    for(int jj=0;jj<32;jj++){
      int j = half*128 + (jg<<5) + ((jj + (jg<<3)) & 31);  // rotated: aW bank-spread
      float a = aW[h*NN + j];
      float4 vv = *(const float4*)(vb + j*INNER);
      FMA4(acc, a, vv);
    }
#pragma unroll
    for(int o=16;o<64;o<<=1){
      acc.x += __shfl_xor(acc.x,o); acc.y += __shfl_xor(acc.y,o);
      acc.z += __shfl_xor(acc.z,o); acc.w += __shfl_xor(acc.w,o);
    }
    if(l<16) *(float4*)(aoP + (half*NH + h)*DH + dq) = acc;
  }
  __syncthreads();                               // B5
  if(t < INNER){
    const int c = t, h2 = c>>6, d = c&63;
    ao[c] = aoP[h2*DH + d] + aoP[(NH+h2)*DH + d]
          + cEs[h2*3+0]*We[0*INNER+c] + cEs[h2*3+1]*We[1*INNER+c]
          + cEs[h2*3+2]*We[2*INNER+c];
  }
  __syncthreads();                               // B6 (ao ready; SC free)

  // ---- Wo + gate1 + LN2 ----
  mvp512_128(ao, Wo, SC, t);
  __syncthreads();                               // B7
  if(t < DIM){
    float s = bo[t];
#pragma unroll
    for(int fg=0; fg<32; fg++) s += SC[fg*DIM + t];
    o128[t] = s;
  }
  __syncthreads();                               // B8
  {
    float o0 = o128[l], o1 = o128[64+l];
    gate_wave(o0, o1, nd0, nd1, Wg1, l);
    float x0, x1;
    ln_wave(nd0, nd1, ln2_g, ln2_b, l, x0, x1);
    xsm[l] = x0; xsm[64+l] = x1;
  }
  __syncthreads();                               // B9 (xsm ready; SC free)

  // ---- FFN ----
  mvp128_512(xsm, W1, SC, t);
  __syncthreads();                               // B10
  if(t < INNER){
    float a = b1[t];
#pragma unroll
    for(int fo=0; fo<8; fo++) a += SC[fo*INNER + t];
    qs[t] = 0.5f*a*(1.f + erff(a*0.70710678118654752440f));
  }
  __syncthreads();                               // B11 (hidden ready; SC free)
  mvp512_128(qs, W2, SC, t);
  __syncthreads();                               // B12
  if(t < DIM){
    float s = b2[t];
#pragma unroll
    for(int fg=0; fg<32; fg++) s += SC[fg*DIM + t];
    o128[t] = s;
  }
  __syncthreads();                               // B13
  {
    float y0 = o128[l], y1 = o128[64+l];
    gate_wave(y0, y1, nd0, nd1, Wg2, l);
    if(w==0){ nodes[i*DIM + l] = nd0; nodes[i*DIM + 64 + l] = nd1; }
    if(has_next){
      float x0, x1;
      ln_wave(nd0, nd1, ln1_g_n, ln1_b_n, l, x0, x1);
      xsm[l] = x0; xsm[64+l] = x1;
    } else if(w==0){
      float ev = nd0*out_w[l] + nd1*out_w[64+l];
      ev = wred_sum(ev);
      if(l==0) eout[i] = ev + out_b[0];
    }
  }
  if(has_next){
    __syncthreads();                             // B14 (xsm ready; SC free)
    qkv_tail(xsm, i, Wq_n, bq_n, Wkv_n, bkv_n, be_n,
             qg_n, kT_n, vg_n, SC, t);           // B15-B17
  }
}

extern "C" void kernel_launch(void* const* d_in, const int* in_sizes, int n_in,
                              void* d_out, int out_size, void* d_ws, size_t ws_size,
                              hipStream_t stream){
  const float* coords   = (const float*)d_in[0];
  const int*   bonds    = (const int*  )d_in[1];
  const float* noise    = (const float*)d_in[2];
  const float* atom_emb = (const float*)d_in[3];
  const float* ln1_g = (const float*)d_in[4];
  const float* ln1_b = (const float*)d_in[5];
  const float* Wq    = (const float*)d_in[6];
  const float* bq    = (const float*)d_in[7];
  const float* Wkv   = (const float*)d_in[8];
  const float* bkv   = (const float*)d_in[9];
  const float* We    = (const float*)d_in[10];
  const float* be    = (const float*)d_in[11];
  const float* Wo    = (const float*)d_in[12];
  const float* bo    = (const float*)d_in[13];
  const float* Wg1   = (const float*)d_in[14];
  const float* ln2_g = (const float*)d_in[15];
  const float* ln2_b = (const float*)d_in[16];
  const float* W1    = (const float*)d_in[17];
  const float* b1    = (const float*)d_in[18];
  const float* W2    = (const float*)d_in[19];
  const float* b2    = (const float*)d_in[20];
  const float* Wg2   = (const float*)d_in[21];
  const float* out_w = (const float*)d_in[22];
  const float* out_b = (const float*)d_in[23];

  // workspace (fp32): ~3.3 MB
  float* ws = (float*)d_ws;
  float* nodes   = ws;                              // 32768 floats
  float* qbuf[2] = { ws +  32768, ws + 163840 };    // 131072 each
  float* kbuf[2] = { ws + 294912, ws + 425984 };    // transposed [c][j]
  float* vbuf[2] = { ws + 557056, ws + 688128 };    // row-major [j][c]

  k_qkv0<<<NN, TB, 0, stream>>>(atom_emb, noise, nodes, ln1_g, ln1_b,
                                Wq, bq, Wkv, bkv, be,
                                qbuf[0], kbuf[0], vbuf[0]);
  for(int l=0; l<DEPTH; l++){
    int cur = l&1, nxt = cur^1;
    int has_next = (l < DEPTH-1);
    int ln = has_next ? l+1 : l;    // keep pointers valid when unused
    k_layer<<<NN, TB, 0, stream>>>(
      nodes, qbuf[cur], kbuf[cur], vbuf[cur],
      qbuf[nxt], kbuf[nxt], vbuf[nxt],
      bonds, coords,
      We  + (size_t)l*3*INNER,
      Wo  + (size_t)l*INNER*DIM, bo + (size_t)l*DIM, Wg1 + (size_t)l*3*DIM,
      ln2_g + (size_t)l*DIM, ln2_b + (size_t)l*DIM,
      W1  + (size_t)l*DIM*4*DIM, b1 + (size_t)l*4*DIM,
      W2  + (size_t)l*4*DIM*DIM, b2 + (size_t)l*DIM, Wg2 + (size_t)l*3*DIM,
      ln1_g + (size_t)ln*DIM, ln1_b + (size_t)ln*DIM,
      Wq  + (size_t)ln*DIM*INNER, bq + (size_t)ln*INNER,
      Wkv + (size_t)ln*DIM*2*INNER, bkv + (size_t)ln*2*INNER,
      be  + (size_t)ln*INNER,
      out_w, out_b, (float*)d_out, has_next);
  }
}

// Round 5
// 303.597 us; speedup vs baseline: 1.0613x; 1.0613x over previous
//
#include <hip/hip_runtime.h>

#define NN     256
#define NF     127
#define DIM    128
#define NH     8
#define DH     64
#define INNER  512
#define DEPTH  6
#define NB     512
#define ATTN_SCALE 0.125f
#define LN_EPS 1e-5f

#define FMA4(A_, S_, V_) { A_.x=fmaf(S_,(V_).x,A_.x); A_.y=fmaf(S_,(V_).y,A_.y); \
                           A_.z=fmaf(S_,(V_).z,A_.z); A_.w=fmaf(S_,(V_).w,A_.w); }

__device__ __forceinline__ float wred_sum(float v){
#pragma unroll
  for(int o=32;o;o>>=1) v += __shfl_xor(v,o);
  return v;
}
__device__ __forceinline__ float wred_max(float v){
#pragma unroll
  for(int o=32;o;o>>=1) v = fmaxf(v,__shfl_xor(v,o));
  return v;
}
__device__ __forceinline__ float2 wred_sum2(float a, float b){
#pragma unroll
  for(int o=32;o;o>>=1){ a += __shfl_xor(a,o); b += __shfl_xor(b,o); }
  return make_float2(a,b);
}

// In-wave LayerNorm of a 128-dim row held as (n0,n1) = dims (l, l+64) per lane.
__device__ __forceinline__ void ln_wave(float n0, float n1,
                                        const float* g, const float* b, int l,
                                        float& x0, float& x1){
  float2 sv = wred_sum2(n0+n1, n0*n0+n1*n1);
  float m  = sv.x*(1.f/DIM);
  float var = sv.y*(1.f/DIM) - m*m;
  float rs = rsqrtf(var + LN_EPS);
  x0 = (n0-m)*rs*g[l]    + b[l];
  x1 = (n1-m)*rs*g[64+l] + b[64+l];
}

// In-wave gated residual. No barriers.
__device__ __forceinline__ void gate_wave(float o0, float o1, float& n0, float& n1,
                                          const float* Wg, int l){
  float gv = o0*Wg[l]    + n0*Wg[DIM+l]    + (o0-n0)*Wg[2*DIM+l]
           + o1*Wg[64+l] + n1*Wg[DIM+64+l] + (o1-n1)*Wg[2*DIM+64+l];
  gv = wred_sum(gv);
  float gate = 1.f/(1.f + expf(-gv));
  n0 = o0*gate + n0*(1.f-gate);
  n1 = o1*gate + n1*(1.f-gate);
}

// ---- matvec partials, 512-thread variants (SC = 2048 floats) ----
// x[128] @ W[128][512] -> SC[fq*512+c], fq in [0,4)
__device__ __forceinline__ void mvp128_512(const float* xin, const float* W,
                                           float* SC, int t){
  const int cg4 = (t&127)<<2, fq = t>>7;
  float4 acc = make_float4(0.f,0.f,0.f,0.f);
#pragma unroll 8
  for(int f=fq*32; f<fq*32+32; f++){
    float4 wv = *(const float4*)(W + f*INNER + cg4);
    float xv = xin[f];
    FMA4(acc, xv, wv);
  }
  *(float4*)(SC + fq*INNER + cg4) = acc;
}
// x[128] @ W[128][1024] -> SC[rh*1024+c], rh in [0,2)
__device__ __forceinline__ void mvp128_1024(const float* xin, const float* W,
                                            float* SC, int t){
  const int cg4 = (t&255)<<2, rh = t>>8;
  float4 acc = make_float4(0.f,0.f,0.f,0.f);
#pragma unroll 8
  for(int f=rh*64; f<rh*64+64; f++){
    float4 wv = *(const float4*)(W + f*(2*INNER) + cg4);
    float xv = xin[f];
    FMA4(acc, xv, wv);
  }
  *(float4*)(SC + rh*(2*INNER) + cg4) = acc;
}
// a[512] @ W[512][128] -> SC[fg*128+c], fg in [0,16)
__device__ __forceinline__ void mvp512_128(const float* ain, const float* W,
                                           float* SC, int t){
  const int cg4 = (t&31)<<2, fg = t>>5;
  float4 acc = make_float4(0.f,0.f,0.f,0.f);
#pragma unroll 8
  for(int f=fg*32; f<fg*32+32; f++){
    float4 wv = *(const float4*)(W + f*DIM + cg4);
    float av = ain[f];
    FMA4(acc, av, wv);
  }
  *(float4*)(SC + fg*DIM + cg4) = acc;
}

// LN1 output xs[128] (LDS) -> next-layer q/k/v. 3 barriers inside.
__device__ __forceinline__ void qkv_tail(const float* xs, int i,
    const float* Wq, const float* bq, const float* Wkv, const float* bkv,
    const float* be, float* qgn, float* kTn, float* vgn, float* SC, int t){
  mvp128_512(xs, Wq, SC, t);
  __syncthreads();
  qgn[i*INNER + t] = bq[t] + SC[t] + SC[INNER+t] + SC[2*INNER+t] + SC[3*INNER+t];
  __syncthreads();                 // SC reuse
  mvp128_1024(xs, Wkv, SC, t);
  __syncthreads();
#pragma unroll
  for(int cc=0; cc<2; cc++){
    int c = t + cc*512;
    float s = bkv[c] + SC[c] + SC[2*INNER+c];
    if(c < INNER) kTn[c*NN + i]            = s + be[c];
    else          vgn[i*INNER + c - INNER] = s + be[c-INNER];
  }
}

// ---- layer 0: node-init + LN1 (in-wave) + QKV ----
__global__ __launch_bounds__(512) void k_qkv0(const float* atom_emb, const float* noise,
    float* nodes, const float* ln1_g, const float* ln1_b,
    const float* Wq, const float* bq, const float* Wkv, const float* bkv, const float* be,
    float* qg, float* kT, float* vg){
  __shared__ __align__(16) float SC[2048];
  __shared__ __align__(16) float xsm[DIM];
  const int t = threadIdx.x, i = blockIdx.x;
  const int w = t>>6, l = t&63;
  float nd0 = (l<NF)?    atom_emb[i*NF + l]      : noise[0];
  float nd1 = (64+l<NF)? atom_emb[i*NF + 64 + l] : noise[0];
  if(w==0){ nodes[i*DIM + l] = nd0; nodes[i*DIM + 64 + l] = nd1; }
  float x0, x1;
  ln_wave(nd0, nd1, ln1_g, ln1_b, l, x0, x1);
  xsm[l] = x0; xsm[64+l] = x1;     // all waves write identical values (benign)
  __syncthreads();
  qkv_tail(xsm, i, Wq, bq, Wkv, bkv, be, qg, kT, vg, SC, t);
}

// ---- attention kernel: block = (head h, 8-row tile); wave w = row i0+w ----
// Each block reads only its head's K/V slices (64KB each) -> 34MB aggregate.
__global__ __launch_bounds__(512) void k_attn(
    const float* qg, const float* kT, const float* vg,
    const int* bonds, const float* coords, const float* We,
    float* aog)
{
  __shared__ __align__(16) float qsm[8*DH];     // q head-slice, 8 rows
  __shared__ __align__(16) float eb[8][3*NN];   // per-row edge planes [x|y|z]
  __shared__ __align__(16) float aW[8][NN];     // attn weights per row
  const int t = threadIdx.x;
  const int h = blockIdx.x >> 5, i0 = (blockIdx.x & 31) << 3;
  const int w = t>>6, l = t&63;
  const int qb = h*DH, j0 = l<<2;

  qsm[w*DH + l] = qg[(i0+w)*INNER + qb + l];
#pragma unroll
  for(int cc=0; cc<12; cc++) (&eb[0][0])[cc*512 + t] = 0.f;   // 8*768 = 6144
  __syncthreads();

  // bond scatter for rows i0..i0+7 (duplicates carry identical values)
  {
    const int bi = bonds[2*t], bj = bonds[2*t+1];
    const bool hi = (bi>=i0 && bi<i0+8), hj = (bj>=i0 && bj<i0+8);
    if(hi || hj){
      float dx = coords[3*bi+0] - coords[3*bj+0];
      float dy = coords[3*bi+1] - coords[3*bj+1];
      float dz = coords[3*bi+2] - coords[3*bj+2];
      if(hi){ float* e = eb[bi-i0]; e[bj]=dx;  e[NN+bj]=dy;  e[2*NN+bj]=dz;  }
      if(hj){ float* e = eb[bj-i0]; e[bi]=-dx; e[NN+bi]=-dy; e[2*NN+bi]=-dz; }
    }
  }
  __syncthreads();

  // qwe_c = q_row . We[c, h-slice]  (in-wave butterfly)
  float qwe0, qwe1, qwe2;
  {
    float qv = qsm[w*DH + l];
    qwe0 = qv*We[0*INNER + qb + l];
    qwe1 = qv*We[1*INNER + qb + l];
    qwe2 = qv*We[2*INNER + qb + l];
#pragma unroll
    for(int o=32;o;o>>=1){
      qwe0 += __shfl_xor(qwe0,o); qwe1 += __shfl_xor(qwe1,o); qwe2 += __shfl_xor(qwe2,o);
    }
  }
  // QK^T: lane l -> scores j0..j0+3 for row i0+w (kT slice shared by all 8 waves via L1)
  const float* kTh = kT + qb*NN;
  float s0=0.f,s1=0.f,s2=0.f,s3=0.f;
#pragma unroll 8
  for(int o=0;o<DH;o++){
    float qv = qsm[w*DH + o];
    float4 kk = *(const float4*)(kTh + o*NN + j0);
    s0=fmaf(qv,kk.x,s0); s1=fmaf(qv,kk.y,s1); s2=fmaf(qv,kk.z,s2); s3=fmaf(qv,kk.w,s3);
  }
  const float* e = eb[w];
  float4 ex = *(const float4*)(e + j0);
  float4 ey = *(const float4*)(e + NN + j0);
  float4 ez = *(const float4*)(e + 2*NN + j0);
  s0 = (s0 + qwe0*ex.x + qwe1*ey.x + qwe2*ez.x)*ATTN_SCALE;
  s1 = (s1 + qwe0*ex.y + qwe1*ey.y + qwe2*ez.y)*ATTN_SCALE;
  s2 = (s2 + qwe0*ex.z + qwe1*ey.z + qwe2*ez.z)*ATTN_SCALE;
  s3 = (s3 + qwe0*ex.w + qwe1*ey.w + qwe2*ez.w)*ATTN_SCALE;
  float mx = wred_max(fmaxf(fmaxf(s0,s1),fmaxf(s2,s3)));
  float p0=expf(s0-mx), p1=expf(s1-mx), p2=expf(s2-mx), p3=expf(s3-mx);
  float inv = 1.f / wred_sum(p0+p1+p2+p3);
  float a0=p0*inv, a1=p1*inv, a2=p2*inv, a3=p3*inv;
  *(float4*)(aW[w] + j0) = make_float4(a0,a1,a2,a3);
  // edge moments c_c = sum_j a_j * eb[c][j]
  float c0 = a0*ex.x + a1*ex.y + a2*ex.z + a3*ex.w;
  float c1 = a0*ey.x + a1*ey.y + a2*ey.z + a3*ey.w;
  float c2 = a0*ez.x + a1*ez.y + a2*ez.z + a3*ez.w;
  c0 = wred_sum(c0); c1 = wred_sum(c1); c2 = wred_sum(c2);
  __builtin_amdgcn_wave_barrier();   // order aW writes before same-wave aW reads
  // PV: lane l -> dims dq..dq+3, rotated j-start spreads aW banks
  const int dq = (l&15)<<2, jg = l>>4;
  const float* vb = vg + qb + dq;
  float4 acc = make_float4(0.f,0.f,0.f,0.f);
#pragma unroll 8
  for(int jj=0;jj<64;jj++){
    int j = (jg<<6) + ((jj + (jg<<3)) & 63);
    float a = aW[w][j];
    float4 vv = *(const float4*)(vb + j*INNER);
    FMA4(acc, a, vv);
  }
#pragma unroll
  for(int o=16;o<64;o<<=1){
    acc.x += __shfl_xor(acc.x,o); acc.y += __shfl_xor(acc.y,o);
    acc.z += __shfl_xor(acc.z,o); acc.w += __shfl_xor(acc.w,o);
  }
  if(l<16){
    float4 we0 = *(const float4*)(We + 0*INNER + qb + dq);
    float4 we1 = *(const float4*)(We + 1*INNER + qb + dq);
    float4 we2 = *(const float4*)(We + 2*INNER + qb + dq);
    float4 ov;
    ov.x = acc.x + c0*we0.x + c1*we1.x + c2*we2.x;
    ov.y = acc.y + c0*we0.y + c1*we1.y + c2*we2.y;
    ov.z = acc.z + c0*we0.z + c1*we1.z + c2*we2.z;
    ov.w = acc.w + c0*we0.w + c1*we1.w + c2*we2.w;
    *(float4*)(aog + (i0+w)*INNER + qb + dq) = ov;
  }
}

// ---- fused per-row layer tail: Wo+gate1+LN2+FFN+gate2 (+next QKV | energy) ----
__global__ __launch_bounds__(512) void k_layer(
    float* nodes, const float* aog,
    float* qg_n, float* kT_n, float* vg_n,
    const float* Wo, const float* bo, const float* Wg1,
    const float* ln2_g, const float* ln2_b,
    const float* W1, const float* b1, const float* W2, const float* b2,
    const float* Wg2,
    const float* ln1_g_n, const float* ln1_b_n,
    const float* Wq_n, const float* bq_n, const float* Wkv_n, const float* bkv_n,
    const float* be_n,
    const float* out_w, const float* out_b, float* eout, int has_next)
{
  __shared__ __align__(16) float SC[2048];   // matmul partials
  __shared__ __align__(16) float qs[INNER];  // FFN hidden
  __shared__ __align__(16) float aos[INNER]; // attention output row
  __shared__ __align__(16) float xsm[DIM];
  const int t = threadIdx.x, i = blockIdx.x;
  const int w = t>>6, l = t&63;

  aos[t] = aog[i*INNER + t];
  float nd0 = nodes[i*DIM + l];        // per-wave redundant row state
  float nd1 = nodes[i*DIM + 64 + l];
  __syncthreads();                               // B1

  // ---- Wo + gate1 + LN2 ----
  mvp512_128(aos, Wo, SC, t);
  __syncthreads();                               // B2
  {
    float o0 = bo[l], o1 = bo[64+l];
#pragma unroll
    for(int fg=0; fg<16; fg++){ o0 += SC[fg*DIM + l]; o1 += SC[fg*DIM + 64 + l]; }
    gate_wave(o0, o1, nd0, nd1, Wg1, l);
    float x0, x1;
    ln_wave(nd0, nd1, ln2_g, ln2_b, l, x0, x1);
    xsm[l] = x0; xsm[64+l] = x1;
  }
  __syncthreads();                               // B3 (xsm ready; SC free)

  // ---- FFN ----
  mvp128_512(xsm, W1, SC, t);
  __syncthreads();                               // B4
  {
    float a = b1[t] + SC[t] + SC[INNER+t] + SC[2*INNER+t] + SC[3*INNER+t];
    qs[t] = 0.5f*a*(1.f + erff(a*0.70710678118654752440f));
  }
  __syncthreads();                               // B5 (hidden ready; SC free)
  mvp512_128(qs, W2, SC, t);
  __syncthreads();                               // B6
  {
    float y0 = b2[l], y1 = b2[64+l];
#pragma unroll
    for(int fg=0; fg<16; fg++){ y0 += SC[fg*DIM + l]; y1 += SC[fg*DIM + 64 + l]; }
    gate_wave(y0, y1, nd0, nd1, Wg2, l);
    if(w==0){ nodes[i*DIM + l] = nd0; nodes[i*DIM + 64 + l] = nd1; }
    if(has_next){
      float x0, x1;
      ln_wave(nd0, nd1, ln1_g_n, ln1_b_n, l, x0, x1);
      xsm[l] = x0; xsm[64+l] = x1;
    } else if(w==0){
      float ev = nd0*out_w[l] + nd1*out_w[64+l];
      ev = wred_sum(ev);
      if(l==0) eout[i] = ev + out_b[0];
    }
  }
  if(has_next){
    __syncthreads();                             // B7 (xsm ready; SC free)
    qkv_tail(xsm, i, Wq_n, bq_n, Wkv_n, bkv_n, be_n,
             qg_n, kT_n, vg_n, SC, t);           // B8-B10
  }
}

extern "C" void kernel_launch(void* const* d_in, const int* in_sizes, int n_in,
                              void* d_out, int out_size, void* d_ws, size_t ws_size,
                              hipStream_t stream){
  const float* coords   = (const float*)d_in[0];
  const int*   bonds    = (const int*  )d_in[1];
  const float* noise    = (const float*)d_in[2];
  const float* atom_emb = (const float*)d_in[3];
  const float* ln1_g = (const float*)d_in[4];
  const float* ln1_b = (const float*)d_in[5];
  const float* Wq    = (const float*)d_in[6];
  const float* bq    = (const float*)d_in[7];
  const float* Wkv   = (const float*)d_in[8];
  const float* bkv   = (const float*)d_in[9];
  const float* We    = (const float*)d_in[10];
  const float* be    = (const float*)d_in[11];
  const float* Wo    = (const float*)d_in[12];
  const float* bo    = (const float*)d_in[13];
  const float* Wg1   = (const float*)d_in[14];
  const float* ln2_g = (const float*)d_in[15];
  const float* ln2_b = (const float*)d_in[16];
  const float* W1    = (const float*)d_in[17];
  const float* b1    = (const float*)d_in[18];
  const float* W2    = (const float*)d_in[19];
  const float* b2    = (const float*)d_in[20];
  const float* Wg2   = (const float*)d_in[21];
  const float* out_w = (const float*)d_in[22];
  const float* out_b = (const float*)d_in[23];

  // workspace (fp32): ~3.7 MB
  float* ws = (float*)d_ws;
  float* nodes   = ws;                              // 32768 floats
  float* qbuf[2] = { ws +  32768, ws + 163840 };    // 131072 each
  float* kbuf[2] = { ws + 294912, ws + 425984 };    // transposed [c][j]
  float* vbuf[2] = { ws + 557056, ws + 688128 };    // row-major [j][c]
  float* aobuf   = ws + 819200;                     // 131072 (attention out)

  k_qkv0<<<NN, 512, 0, stream>>>(atom_emb, noise, nodes, ln1_g, ln1_b,
                                 Wq, bq, Wkv, bkv, be,
                                 qbuf[0], kbuf[0], vbuf[0]);
  for(int l=0; l<DEPTH; l++){
    int cur = l&1, nxt = cur^1;
    int has_next = (l < DEPTH-1);
    int ln = has_next ? l+1 : l;    // keep pointers valid when unused
    k_attn<<<NN, 512, 0, stream>>>(
      qbuf[cur], kbuf[cur], vbuf[cur], bonds, coords,
      We + (size_t)l*3*INNER, aobuf);
    k_layer<<<NN, 512, 0, stream>>>(
      nodes, aobuf,
      qbuf[nxt], kbuf[nxt], vbuf[nxt],
      Wo  + (size_t)l*INNER*DIM, bo + (size_t)l*DIM, Wg1 + (size_t)l*3*DIM,
      ln2_g + (size_t)l*DIM, ln2_b + (size_t)l*DIM,
      W1  + (size_t)l*DIM*4*DIM, b1 + (size_t)l*4*DIM,
      W2  + (size_t)l*4*DIM*DIM, b2 + (size_t)l*DIM, Wg2 + (size_t)l*3*DIM,
      ln1_g + (size_t)ln*DIM, ln1_b + (size_t)ln*DIM,
      Wq  + (size_t)ln*DIM*INNER, bq + (size_t)ln*INNER,
      Wkv + (size_t)ln*DIM*2*INNER, bkv + (size_t)ln*2*INNER,
      be  + (size_t)ln*INNER,
      out_w, out_b, (float*)d_out, has_next);
  }
}